// Round 7
// baseline (103.962 us; speedup 1.0000x reference)
//
#include <hip/hip_runtime.h>
#include <hip/hip_bf16.h>

#define H_DIM   64
#define T_STEPS 128
#define B_TOT   4096
#define BB      16    // rows per block (full M tile)
#define SK      72    // padded row stride in halves for sX/sH
#define NTHREADS 1024 // 16 waves; wave w owns h-cols w*4..w*4+3, all 4 gates in ONE N-tile

typedef _Float16 half8  __attribute__((ext_vector_type(8)));
typedef __fp16   fp16x2 __attribute__((ext_vector_type(2)));
typedef __attribute__((ext_vector_type(4))) float f32x4;

#if __has_builtin(__builtin_amdgcn_exp2f)
#define EXP2(x) __builtin_amdgcn_exp2f(x)
#else
#define EXP2(x) exp2f(x)
#endif

// Weights/biases are pre-scaled by log2(e) (i,f,o) or 2*log2(e) (g), so the
// activations are raw exp2-domain: no per-activation multiply.
__device__ __forceinline__ float sigmoid2(float xp) {      // xp = x*log2e
    return __builtin_amdgcn_rcpf(1.0f + EXP2(-xp));        // exact at +-inf
}
__device__ __forceinline__ float tanh2(float xp) {         // xp = 2*log2e*x
    return fmaf(-2.0f, __builtin_amdgcn_rcpf(EXP2(xp) + 1.0f), 1.0f);
}

// A = [x (64) | h (64)] f16, K=128, M=16 rows, 16 waves.
// B-fragment packs FOUR gates' 4-col slices per 16-wide N-tile:
//   n = lrow: gate = lrow>>2, col = w*4 + (lrow&3)
// Gate gather = 4x4 cross-lane transpose over lanes {l, l^4, l^8, l^12}.
// Each thread then updates ONE (row,col): row = lk*4 + (lrow>>2), col as above.
__global__ __launch_bounds__(NTHREADS) void lstm_fused(
    const int* __restrict__ inst, const float* __restrict__ embed,
    const float* __restrict__ Wih, const float* __restrict__ Whh,
    const float* __restrict__ bih, const float* __restrict__ bhh,
    float* __restrict__ out)
{
    __shared__ __align__(16) _Float16 sX[2][BB][SK];   // 4.6 KB  x staging (f16)
    __shared__ __align__(16) _Float16 sH[2][BB][SK];   // 4.6 KB  h staging (f16)
    __shared__ int sInst[BB * T_STEPS];                // 8 KB

    const int tid  = (int)threadIdx.x;
    const int w    = tid >> 6;          // wave 0..15; also the x-staging row
    const int l    = tid & 63;
    const int lrow = l & 15;            // packed-n for B & C/D; A-row (m) for reads
    const int lk   = l >> 4;            // k-block; C/D rows are lk*4 + 0..3
    const int g4   = lrow >> 2;         // lane's gate index == its row assignment
    const bool g0  = g4 & 1;
    const bool g1  = (g4 >> 1) & 1;
    const int col  = w * 4 + (lrow & 3);   // h-column this thread updates
    const int row  = lk * 4 + g4;          // h-row this thread updates
    const int b0   = (int)blockIdx.x * BB;

    const float L2E = 1.4426950408889634f;

    // stage this block's instruction indices (16 rows x 128 steps, contiguous)
    for (int i = tid; i < BB * T_STEPS; i += NTHREADS)
        sInst[i] = inst[b0 * T_STEPS + i];

    // zero h buffer 0 (h0 = 0); sH[1] fully overwritten each step
    for (int i = tid; i < BB * SK; i += NTHREADS)
        ((_Float16*)sH)[i] = (_Float16)0.0f;
    __syncthreads();

    // weight B-fragments (f16, pre-scaled): gate g4, col-in-gate `col`
    // kf 0,1 -> W_ih k 0..63 ; kf 2,3 -> W_hh k 0..63
    const float wscale = (g4 == 2) ? 2.0f * L2E : L2E;   // g gate feeds tanh(2x form)
    half8 wf[4];
    float bias;
    {
        const int gcol = g4 * 64 + col;                  // W output row 0..255
        bias = (bih[gcol] + bhh[gcol]) * wscale;
#pragma unroll
        for (int kf = 0; kf < 4; ++kf) {
            const float* src = (kf < 2 ? Wih : Whh) + (long)gcol * H_DIM + (kf & 1) * 32 + lk * 8;
            half8 v;
#pragma unroll
            for (int j = 0; j < 8; ++j) v[j] = (_Float16)(src[j] * wscale);
            wf[kf] = v;
        }
    }

    // x staging: wave w handles block-row w, lane l handles feature l (coalesced)
    {
        const int idx = __builtin_amdgcn_readfirstlane(sInst[w * T_STEPS + 0]);
        sX[0][w][l] = (_Float16)embed[(long)idx * H_DIM + l];
    }
    __syncthreads();

    float creg = 0.f, hreg = 0.f;

    for (int t = 0; t < T_STEPS; ++t) {
        const int buf = t & 1;
        const int ob  = buf ^ 1;
        const bool pf = (t + 1 < T_STEPS);

        // prefetch next step's x feature (global -> reg), hidden under MFMA
        float xv = 0.f;
        if (pf) {
            const int idx = __builtin_amdgcn_readfirstlane(sInst[w * T_STEPS + t + 1]);
            xv = embed[(long)idx * H_DIM + l];
        }

        // A-fragments (f16): lane (m=lrow, lk) reads 16B contiguous
        half8 a0 = *reinterpret_cast<const half8*>(&sX[buf][lrow][lk * 8]);
        half8 a1 = *reinterpret_cast<const half8*>(&sX[buf][lrow][32 + lk * 8]);
        half8 a2 = *reinterpret_cast<const half8*>(&sH[buf][lrow][lk * 8]);
        half8 a3 = *reinterpret_cast<const half8*>(&sH[buf][lrow][32 + lk * 8]);

        // one packed 4-gate tile; two 2-deep MFMA chains for ILP
        f32x4 pA = {bias, bias, bias, bias};
        f32x4 pB = {0.f, 0.f, 0.f, 0.f};
        pA = __builtin_amdgcn_mfma_f32_16x16x32_f16(a0, wf[0], pA, 0, 0, 0);
        pB = __builtin_amdgcn_mfma_f32_16x16x32_f16(a1, wf[1], pB, 0, 0, 0);
        pA = __builtin_amdgcn_mfma_f32_16x16x32_f16(a2, wf[2], pA, 0, 0, 0);
        pB = __builtin_amdgcn_mfma_f32_16x16x32_f16(a3, wf[3], pB, 0, 0, 0);
        const f32x4 acc = pA + pB;   // acc[r] = gate g4 at row lk*4+r, col `col`

        // 4x4 transpose over lanes {l, l^4, l^8, l^12}:
        // start: lane(gate G) holds acc[r] = A[G][r]; end: lane holds C[q] = A[q][G].
        // Stage 1 (lane-bit g0 <-> element-bit r0), 2 shfls with pre-mux:
        const float s1a = g0 ? acc[0] : acc[1];           // send: partner's needed elem
        const float s1b = g0 ? acc[2] : acc[3];
        const float r1a = __shfl_xor(s1a, 4);
        const float r1b = __shfl_xor(s1b, 4);
        const float B0 = g0 ? r1a : acc[0];
        const float B1 = g0 ? acc[1] : r1a;
        const float B2 = g0 ? r1b : acc[2];
        const float B3 = g0 ? acc[3] : r1b;
        // Stage 2 (lane-bit g1 <-> element-bit r1):
        const float s2a = g1 ? B0 : B2;
        const float s2b = g1 ? B1 : B3;
        const float r2a = __shfl_xor(s2a, 8);
        const float r2b = __shfl_xor(s2b, 8);
        const float vi = g1 ? r2a : B0;
        const float vf = g1 ? r2b : B1;
        const float vg = g1 ? B2 : r2a;
        const float vo = g1 ? B3 : r2b;

        // cell update for this thread's single (row, col); exp2-domain activations
        const float iv = sigmoid2(vi);
        const float fv = sigmoid2(vf);
        const float gv = tanh2(vg);
        const float ov = sigmoid2(vo);
        const float cn = fv * creg + iv * gv;
        creg = cn;
        hreg = ov * tanh2(cn * (2.0f * L2E));

        if (pf) {
            sH[ob][row][col] = (_Float16)hreg;            // publish h (f16, RNE)
            sX[ob][w][l] = (_Float16)xv;                  // publish prefetched x
        }
        __syncthreads();   // sX/sH[ob] visible before next step
    }

    // final h (f32) -> out[B][H]; each thread owns one (row, col)
    out[(long)(b0 + row) * H_DIM + col] = hreg;
}

extern "C" void kernel_launch(void* const* d_in, const int* in_sizes, int n_in,
                              void* d_out, int out_size, void* d_ws, size_t ws_size,
                              hipStream_t stream) {
    const int*   inst  = (const int*)  d_in[0];
    const float* embed = (const float*)d_in[1];
    const float* Wih   = (const float*)d_in[2];
    const float* Whh   = (const float*)d_in[3];
    const float* bih   = (const float*)d_in[4];
    const float* bhh   = (const float*)d_in[5];
    float* out = (float*)d_out;

    lstm_fused<<<B_TOT / BB, NTHREADS, 0, stream>>>(inst, embed, Wih, Whh, bih, bhh, out);
}